// Round 2
// baseline (931.291 us; speedup 1.0000x reference)
//
#include <hip/hip_runtime.h>
#include <stdint.h>
#include <math.h>

#define NB   16
#define CIN  8192
#define CHID 512
#define COUT 100
#define TT   300
#define TG   16
#define NTG  19   // ceil(300/16)

// ---------------- row norms: nrm[row] = sqrt(sum v[row][i]^2) ----------------
__global__ void norm_kernel(const float* __restrict__ v, float* __restrict__ nrm, int cin) {
    int row = blockIdx.x;
    const float* vr = v + (size_t)row * cin;
    float s = 0.f;
    for (int i = threadIdx.x; i < cin; i += 256) {
        float x = vr[i];
        s = __fadd_rn(s, __fmul_rn(x, x));
    }
    __shared__ float red[256];
    red[threadIdx.x] = s;
    __syncthreads();
    for (int off = 128; off > 0; off >>= 1) {
        if (threadIdx.x < off) red[threadIdx.x] += red[threadIdx.x + off];
        __syncthreads();
    }
    if (threadIdx.x == 0) nrm[row] = sqrtf(red[0]);
}

// ------------- transpose + weight-norm scale: wt[i][o] = (v[o][i]*g[o])/nrm[o] -------------
template<int WS>
__global__ void trans_kernel(const float* __restrict__ v, const float* __restrict__ g,
                             const float* __restrict__ nrm, float* __restrict__ wt,
                             int RO, int CI) {
    __shared__ float tile[32][33];
    int i0 = blockIdx.x * 32, o0 = blockIdx.y * 32;
    int tx = threadIdx.x, ty = threadIdx.y;
    for (int k = 0; k < 32; k += 8) {
        int o = o0 + ty + k, i = i0 + tx;
        float val = 0.f;
        if (o < RO) val = __fmul_rn(v[(size_t)o * CI + i], g[o]) / nrm[o];
        tile[ty + k][tx] = val;
    }
    __syncthreads();
    for (int k = 0; k < 32; k += 8) {
        int i = i0 + ty + k, oo = o0 + tx;
        if (oo < WS) wt[(size_t)i * WS + oo] = tile[tx][ty + k];
    }
}

// ------------- sparse spike GEMM: z[b][t][o] = sum_{i: spike(b,i,t)!=0} wt[i][o] -------------
// One block per (t-group of 16, batch b). 512 threads (8 waves).
// Phase 1: each thread builds a 16-bit t-mask for its input channels, ballot-compacts
//          (i<<16|mask) entries into per-wave LDS segments (deterministic i-order).
// Phase 2: all waves walk all segments; per active column, coalesced load of wt[i][:],
//          scatter-add into LDS acc[t][tid] (thread-private slots, no atomics).
template<int NI, int WS, bool FP32IN>
__global__ __launch_bounds__(512) void z_kernel(const void* __restrict__ xin,
                                                const float* __restrict__ wt,
                                                float* __restrict__ zout) {
    constexpr int SEG    = NI / 8;                            // i-range per wave
    constexpr int SEGCAP = (NI >= 4096) ? (NI / 16) : (NI / 8); // list capacity per wave
    __shared__ uint32_t act[8 * SEGCAP];
    __shared__ int      cnt[8];
    __shared__ float    accs[TG * 512];

    int tg = blockIdx.x, b = blockIdx.y;
    int t0 = tg * TG;
    int nt = min(TG, TT - t0);
    int tid  = threadIdx.x;
    int lane = tid & 63;
    int wv   = tid >> 6;

    #pragma unroll
    for (int k = 0; k < TG; ++k) accs[k * 512 + tid] = 0.f;

    // ---- build compacted active list ----
    int cloc = 0;
    constexpr int PERLANE = NI / 512;
    for (int c = 0; c < PERLANE; ++c) {
        int i = wv * SEG + c * 64 + lane;
        uint32_t m = 0;
        if (FP32IN) {
            const float* sp = (const float*)xin + ((size_t)(b * NI + i)) * TT + t0;
            int nq = nt >> 2;  // nt is always a multiple of 4 (16 or 12)
            for (int q = 0; q < nq; ++q) {
                float4 v4 = ((const float4*)sp)[q];
                m |= (uint32_t)(v4.x != 0.f) << (q * 4 + 0);
                m |= (uint32_t)(v4.y != 0.f) << (q * 4 + 1);
                m |= (uint32_t)(v4.z != 0.f) << (q * 4 + 2);
                m |= (uint32_t)(v4.w != 0.f) << (q * 4 + 3);
            }
        } else {
            const uint8_t* sp = (const uint8_t*)xin + ((size_t)b * TT + t0) * NI + i;
            for (int k = 0; k < nt; ++k)
                m |= (uint32_t)(sp[(size_t)k * NI] != 0) << k;
        }
        uint64_t bal = __ballot(m != 0);
        int pos = __popcll(bal & ((1ull << lane) - 1ull));
        if (m) {
            int p = cloc + pos;
            if (p < SEGCAP) act[wv * SEGCAP + p] = ((uint32_t)i << 16) | m;
        }
        cloc += (int)__popcll(bal);
        if (cloc > SEGCAP) cloc = SEGCAP;
    }
    if (lane == 0) cnt[wv] = cloc;
    __syncthreads();

    // ---- accumulate ----
    if (WS == 512 || tid < WS) {
        for (int s8 = 0; s8 < 8; ++s8) {
            int nb = cnt[s8];
            for (int j = 0; j < nb; ++j) {
                uint32_t e = (uint32_t)__builtin_amdgcn_readfirstlane((int)act[s8 * SEGCAP + j]);
                int i      = (int)(e >> 16);
                uint32_t m = e & 0xFFFFu;
                float wval = wt[(size_t)i * WS + tid];
                while (m) {
                    int t = __builtin_ctz(m);
                    m &= m - 1;
                    accs[t * 512 + tid] += wval;  // thread-private slot, exact add (spike==1)
                }
            }
        }
    }
    // each thread only ever wrote its own acc slots -> no barrier needed
    if (tid < WS) {
        for (int k = 0; k < nt; ++k)
            zout[((size_t)b * TT + t0 + k) * WS + tid] = accs[k * 512 + tid];
    }
}

// ---------------- CUBA-LIF scan over T, hidden layers (u8 spikes out) ----------------
__global__ void lif_hidden_kernel(const float* __restrict__ z, uint8_t* __restrict__ x,
                                  const float* __restrict__ cdarr, const float* __restrict__ vdarr,
                                  int li) {
    int gid = blockIdx.x * blockDim.x + threadIdx.x;
    if (gid >= NB * CHID) return;
    int b = gid >> 9, o = gid & 511;
    float omc = 1.0f - cdarr[li];
    float omv = 1.0f - vdarr[li];
    float cur = 0.f, volt = 0.f;
    const float* zp = z + (size_t)b * TT * CHID + o;
    uint8_t* xp = x + (size_t)b * TT * CHID + o;
    for (int t = 0; t < TT; ++t) {
        float zv = zp[(size_t)t * CHID];
        cur  = __fadd_rn(__fmul_rn(omc, cur), zv);
        volt = __fadd_rn(__fmul_rn(omv, volt), cur);
        bool s = (volt >= 1.25f);
        volt = s ? 0.f : volt;
        xp[(size_t)t * CHID] = s ? (uint8_t)1 : (uint8_t)0;
    }
}

// ---------------- CUBA-LIF final layer -> d_out [B][COUT][T] float ----------------
__global__ void lif_out_kernel(const float* __restrict__ z, float* __restrict__ out,
                               const float* __restrict__ cdarr, const float* __restrict__ vdarr,
                               int li) {
    int gid = blockIdx.x * blockDim.x + threadIdx.x;
    if (gid >= NB * COUT) return;
    int b = gid / COUT, o = gid % COUT;
    float omc = 1.0f - cdarr[li];
    float omv = 1.0f - vdarr[li];
    float cur = 0.f, volt = 0.f;
    const float* zp = z + (size_t)b * TT * 128 + o;
    float* op = out + ((size_t)b * COUT + o) * TT;
    for (int t = 0; t < TT; ++t) {
        float zv = zp[(size_t)t * 128];
        cur  = __fadd_rn(__fmul_rn(omc, cur), zv);
        volt = __fadd_rn(__fmul_rn(omv, volt), cur);
        bool s = (volt >= 1.25f);
        volt = s ? 0.f : volt;
        op[t] = s ? 1.0f : 0.0f;
    }
}

extern "C" void kernel_launch(void* const* d_in, const int* in_sizes, int n_in,
                              void* d_out, int out_size, void* d_ws, size_t ws_size,
                              hipStream_t stream) {
    const float* spike = (const float*)d_in[0];
    const float* v1 = (const float*)d_in[1];
    const float* g1 = (const float*)d_in[2];
    const float* v2 = (const float*)d_in[3];
    const float* g2 = (const float*)d_in[4];
    const float* v3 = (const float*)d_in[5];
    const float* g3 = (const float*)d_in[6];
    const float* cd = (const float*)d_in[7];
    const float* vd = (const float*)d_in[8];

    // workspace layout (floats)
    float* ws   = (float*)d_ws;
    float* w1t  = ws;                    // [8192][512]
    float* w2t  = w1t + (size_t)CIN * CHID;      // [512][512]
    float* w3t  = w2t + (size_t)CHID * CHID;     // [512][128]
    float* nrm1 = w3t + (size_t)CHID * 128;      // 512
    float* nrm2 = nrm1 + 512;                    // 512
    float* nrm3 = nrm2 + 512;                    // 128
    float* zbuf = nrm3 + 128;                    // [16][300][512] (z1 then z2)
    float* z3   = zbuf + (size_t)NB * TT * CHID; // [16][300][128]
    uint8_t* x1 = (uint8_t*)(z3 + (size_t)NB * TT * 128);
    uint8_t* x2 = x1 + (size_t)NB * TT * CHID;
    size_t need = (size_t)(x2 + (size_t)NB * TT * CHID - (uint8_t*)d_ws);
    if (ws_size < need) return;  // fail loudly via wrong output rather than corrupt

    // weight prep
    norm_kernel<<<dim3(CHID), dim3(256), 0, stream>>>(v1, nrm1, CIN);
    norm_kernel<<<dim3(CHID), dim3(256), 0, stream>>>(v2, nrm2, CHID);
    norm_kernel<<<dim3(COUT), dim3(256), 0, stream>>>(v3, nrm3, CHID);
    trans_kernel<512><<<dim3(CIN / 32, CHID / 32), dim3(32, 8), 0, stream>>>(v1, g1, nrm1, w1t, CHID, CIN);
    trans_kernel<512><<<dim3(CHID / 32, CHID / 32), dim3(32, 8), 0, stream>>>(v2, g2, nrm2, w2t, CHID, CHID);
    trans_kernel<128><<<dim3(CHID / 32, 4), dim3(32, 8), 0, stream>>>(v3, g3, nrm3, w3t, COUT, CHID);

    dim3 zgrid(NTG, NB);
    // layer 1
    z_kernel<CIN, 512, true><<<zgrid, 512, 0, stream>>>(spike, w1t, zbuf);
    lif_hidden_kernel<<<dim3((NB * CHID + 255) / 256), dim3(256), 0, stream>>>(zbuf, x1, cd, vd, 0);
    // layer 2
    z_kernel<CHID, 512, false><<<zgrid, 512, 0, stream>>>(x1, w2t, zbuf);
    lif_hidden_kernel<<<dim3((NB * CHID + 255) / 256), dim3(256), 0, stream>>>(zbuf, x2, cd, vd, 1);
    // layer 3
    z_kernel<CHID, 128, false><<<zgrid, 512, 0, stream>>>(x2, w3t, z3);
    lif_out_kernel<<<dim3((NB * COUT + 255) / 256), dim3(256), 0, stream>>>(z3, (float*)d_out, cd, vd, 2);
}

// Round 3
// 360.977 us; speedup vs baseline: 2.5799x; 2.5799x over previous
//
#include <hip/hip_runtime.h>
#include <stdint.h>
#include <math.h>

#define NB   16
#define CIN  8192
#define CHID 512
#define COUT 100
#define TT   300
#define TG4  4
#define NTG4 75   // 300/4

// ---------------- row norms: nrm[row] = sqrt(sum v[row][i]^2) ----------------
__global__ void norm_kernel(const float* __restrict__ v, float* __restrict__ nrm, int cin) {
    int row = blockIdx.x;
    const float* vr = v + (size_t)row * cin;
    float s = 0.f;
    for (int i = threadIdx.x; i < cin; i += 256) {
        float x = vr[i];
        s = __fadd_rn(s, __fmul_rn(x, x));
    }
    __shared__ float red[256];
    red[threadIdx.x] = s;
    __syncthreads();
    for (int off = 128; off > 0; off >>= 1) {
        if (threadIdx.x < off) red[threadIdx.x] += red[threadIdx.x + off];
        __syncthreads();
    }
    if (threadIdx.x == 0) nrm[row] = sqrtf(red[0]);
}

// ------------- transpose + weight-norm scale: wt[i][o] = (v[o][i]*g[o])/nrm[o] -------------
template<int WS>
__global__ void trans_kernel(const float* __restrict__ v, const float* __restrict__ g,
                             const float* __restrict__ nrm, float* __restrict__ wt,
                             int RO, int CI) {
    __shared__ float tile[32][33];
    int i0 = blockIdx.x * 32, o0 = blockIdx.y * 32;
    int tx = threadIdx.x, ty = threadIdx.y;
    for (int k = 0; k < 32; k += 8) {
        int o = o0 + ty + k, i = i0 + tx;
        float val = 0.f;
        if (o < RO) val = __fmul_rn(v[(size_t)o * CI + i], g[o]) / nrm[o];
        tile[ty + k][tx] = val;
    }
    __syncthreads();
    for (int k = 0; k < 32; k += 8) {
        int i = i0 + ty + k, oo = o0 + tx;
        if (oo < WS) wt[(size_t)i * WS + oo] = tile[tx][ty + k];
    }
}

// ------------- sparse spike GEMM, TG=4, register accumulators -------------
// Grid (b, tg): 16 x 75 blocks, 512 threads. Phase 1: ballot-compact per-wave
// active lists (i<<4 | 4-bit t-mask), deterministic i-ascending order.
// Phase 2: every thread owns output o=tid; walks all 8 segments with unroll-8
// prefetch (8 independent wt loads in flight); predicated adds into 4 register
// accumulators (compile-time indexed -> no LDS RMW, no scratch).
// Summation order per (t,o) is strictly i-ascending == round-1 kernel (exact).
template<int NI, int WS, bool FP32IN>
__global__ __launch_bounds__(512) void z4_kernel(const void* __restrict__ xin,
                                                 const float* __restrict__ wt,
                                                 float* __restrict__ zout) {
    constexpr int SEG     = NI / 8;                      // i-range per wave
    constexpr int SEGCAP  = (SEG < 192) ? SEG : 192;     // >=13 sigma for p<=0.08
    constexpr int PERLANE = SEG / 64;
    __shared__ uint32_t act[8 * SEGCAP];
    __shared__ int      cnt[8];

    int b  = blockIdx.x;
    int tg = blockIdx.y;
    int t0 = tg * TG4;
    int tid = threadIdx.x, lane = tid & 63, wv = tid >> 6;

    // ---- build compacted active list ----
    int cloc = 0;
    for (int c = 0; c < PERLANE; ++c) {
        int i = wv * SEG + c * 64 + lane;
        uint32_t m = 0;
        if (FP32IN) {
            const float* sp = (const float*)xin + ((size_t)(b * NI + i)) * TT + t0;
            float4 v4 = *(const float4*)sp;   // t0*4 bytes is 16B-aligned
            m |= (v4.x != 0.f) ? 1u : 0u;
            m |= (v4.y != 0.f) ? 2u : 0u;
            m |= (v4.z != 0.f) ? 4u : 0u;
            m |= (v4.w != 0.f) ? 8u : 0u;
        } else {
            const uint8_t* sp = (const uint8_t*)xin + ((size_t)b * TT + t0) * NI + i;
            #pragma unroll
            for (int k = 0; k < 4; ++k)
                m |= (sp[(size_t)k * NI] != 0) ? (1u << k) : 0u;
        }
        uint64_t bal = __ballot(m != 0);
        int pos = __popcll(bal & ((1ull << lane) - 1ull));
        if (m) {
            int p = cloc + pos;
            if (p < SEGCAP) act[wv * SEGCAP + p] = ((uint32_t)i << 4) | m;
        }
        cloc += (int)__popcll(bal);
        if (cloc > SEGCAP) cloc = SEGCAP;
    }
    if (lane == 0) cnt[wv] = cloc;
    __syncthreads();

    // ---- accumulate into registers ----
    float a0 = 0.f, a1 = 0.f, a2 = 0.f, a3 = 0.f;
    if (WS == 512 || tid < WS) {
        for (int s = 0; s < 8; ++s) {
            int nb = cnt[s];
            const uint32_t* segp = act + s * SEGCAP;
            int j = 0;
            for (; j + 8 <= nb; j += 8) {
                // two b128 broadcast reads of 8 entries (32B-aligned: SEGCAP%8==0... 192,64 both %8==0)
                uint4 ea = *(const uint4*)(segp + j);
                uint4 eb = *(const uint4*)(segp + j + 4);
                uint32_t e[8] = {ea.x, ea.y, ea.z, ea.w, eb.x, eb.y, eb.z, eb.w};
                float w[8];
                #pragma unroll
                for (int k = 0; k < 8; ++k)
                    w[k] = wt[(size_t)(e[k] >> 4) * WS + tid];
                #pragma unroll
                for (int k = 0; k < 8; ++k) {
                    uint32_t m = e[k];
                    a0 += (m & 1u) ? w[k] : 0.f;
                    a1 += (m & 2u) ? w[k] : 0.f;
                    a2 += (m & 4u) ? w[k] : 0.f;
                    a3 += (m & 8u) ? w[k] : 0.f;
                }
            }
            for (; j < nb; ++j) {
                uint32_t e = segp[j];
                float w = wt[(size_t)(e >> 4) * WS + tid];
                a0 += (e & 1u) ? w : 0.f;
                a1 += (e & 2u) ? w : 0.f;
                a2 += (e & 4u) ? w : 0.f;
                a3 += (e & 8u) ? w : 0.f;
            }
        }
    }
    if (tid < WS) {
        zout[((size_t)b * TT + t0 + 0) * WS + tid] = a0;
        zout[((size_t)b * TT + t0 + 1) * WS + tid] = a1;
        zout[((size_t)b * TT + t0 + 2) * WS + tid] = a2;
        zout[((size_t)b * TT + t0 + 3) * WS + tid] = a3;
    }
}

// ---------------- CUBA-LIF scan over T, hidden layers (u8 spikes out) ----------------
__global__ void lif_hidden_kernel(const float* __restrict__ z, uint8_t* __restrict__ x,
                                  const float* __restrict__ cdarr, const float* __restrict__ vdarr,
                                  int li) {
    int gid = blockIdx.x * blockDim.x + threadIdx.x;
    if (gid >= NB * CHID) return;
    int b = gid >> 9, o = gid & 511;
    float omc = 1.0f - cdarr[li];
    float omv = 1.0f - vdarr[li];
    float cur = 0.f, volt = 0.f;
    const float* zp = z + (size_t)b * TT * CHID + o;
    uint8_t* xp = x + (size_t)b * TT * CHID + o;
    for (int t = 0; t < TT; ++t) {
        float zv = zp[(size_t)t * CHID];
        cur  = __fadd_rn(__fmul_rn(omc, cur), zv);
        volt = __fadd_rn(__fmul_rn(omv, volt), cur);
        bool s = (volt >= 1.25f);
        volt = s ? 0.f : volt;
        xp[(size_t)t * CHID] = s ? (uint8_t)1 : (uint8_t)0;
    }
}

// ---------------- CUBA-LIF final layer -> d_out [B][COUT][T] float ----------------
__global__ void lif_out_kernel(const float* __restrict__ z, float* __restrict__ out,
                               const float* __restrict__ cdarr, const float* __restrict__ vdarr,
                               int li) {
    int gid = blockIdx.x * blockDim.x + threadIdx.x;
    if (gid >= NB * COUT) return;
    int b = gid / COUT, o = gid % COUT;
    float omc = 1.0f - cdarr[li];
    float omv = 1.0f - vdarr[li];
    float cur = 0.f, volt = 0.f;
    const float* zp = z + (size_t)b * TT * 128 + o;
    float* op = out + ((size_t)b * COUT + o) * TT;
    for (int t = 0; t < TT; ++t) {
        float zv = zp[(size_t)t * 128];
        cur  = __fadd_rn(__fmul_rn(omc, cur), zv);
        volt = __fadd_rn(__fmul_rn(omv, volt), cur);
        bool s = (volt >= 1.25f);
        volt = s ? 0.f : volt;
        op[t] = s ? 1.0f : 0.0f;
    }
}

extern "C" void kernel_launch(void* const* d_in, const int* in_sizes, int n_in,
                              void* d_out, int out_size, void* d_ws, size_t ws_size,
                              hipStream_t stream) {
    const float* spike = (const float*)d_in[0];
    const float* v1 = (const float*)d_in[1];
    const float* g1 = (const float*)d_in[2];
    const float* v2 = (const float*)d_in[3];
    const float* g2 = (const float*)d_in[4];
    const float* v3 = (const float*)d_in[5];
    const float* g3 = (const float*)d_in[6];
    const float* cd = (const float*)d_in[7];
    const float* vd = (const float*)d_in[8];

    // workspace layout (floats)
    float* ws   = (float*)d_ws;
    float* w1t  = ws;                            // [8192][512]
    float* w2t  = w1t + (size_t)CIN * CHID;      // [512][512]
    float* w3t  = w2t + (size_t)CHID * CHID;     // [512][128]
    float* nrm1 = w3t + (size_t)CHID * 128;      // 512
    float* nrm2 = nrm1 + 512;                    // 512
    float* nrm3 = nrm2 + 512;                    // 128
    float* zbuf = nrm3 + 128;                    // [16][300][512] (z1 then z2)
    float* z3   = zbuf + (size_t)NB * TT * CHID; // [16][300][128]
    uint8_t* x1 = (uint8_t*)(z3 + (size_t)NB * TT * 128);
    uint8_t* x2 = x1 + (size_t)NB * TT * CHID;
    size_t need = (size_t)(x2 + (size_t)NB * TT * CHID - (uint8_t*)d_ws);
    if (ws_size < need) return;  // fail loudly via wrong output rather than corrupt

    // weight prep
    norm_kernel<<<dim3(CHID), dim3(256), 0, stream>>>(v1, nrm1, CIN);
    norm_kernel<<<dim3(CHID), dim3(256), 0, stream>>>(v2, nrm2, CHID);
    norm_kernel<<<dim3(COUT), dim3(256), 0, stream>>>(v3, nrm3, CHID);
    trans_kernel<512><<<dim3(CIN / 32, CHID / 32), dim3(32, 8), 0, stream>>>(v1, g1, nrm1, w1t, CHID, CIN);
    trans_kernel<512><<<dim3(CHID / 32, CHID / 32), dim3(32, 8), 0, stream>>>(v2, g2, nrm2, w2t, CHID, CHID);
    trans_kernel<128><<<dim3(CHID / 32, 4), dim3(32, 8), 0, stream>>>(v3, g3, nrm3, w3t, COUT, CHID);

    dim3 zgrid(NB, NTG4);   // b fastest: tg-adjacent blocks share XCD (delta bid = 16 == 0 mod 8)
    // layer 1
    z4_kernel<CIN, 512, true><<<zgrid, 512, 0, stream>>>(spike, w1t, zbuf);
    lif_hidden_kernel<<<dim3((NB * CHID + 255) / 256), dim3(256), 0, stream>>>(zbuf, x1, cd, vd, 0);
    // layer 2
    z4_kernel<CHID, 512, false><<<zgrid, 512, 0, stream>>>(x1, w2t, zbuf);
    lif_hidden_kernel<<<dim3((NB * CHID + 255) / 256), dim3(256), 0, stream>>>(zbuf, x2, cd, vd, 1);
    // layer 3
    z4_kernel<CHID, 128, false><<<zgrid, 512, 0, stream>>>(x2, w3t, z3);
    lif_out_kernel<<<dim3((NB * COUT + 255) / 256), dim3(256), 0, stream>>>(z3, (float*)d_out, cd, vd, 2);
}

// Round 4
// 269.772 us; speedup vs baseline: 3.4521x; 1.3381x over previous
//
#include <hip/hip_runtime.h>
#include <stdint.h>
#include <math.h>

#define NB   16
#define CIN  8192
#define CHID 512
#define COUT 100
#define TT   300
#define TG4  4
#define NTG4 75   // 300/4

// ---------------- row norms: nrm[row] = sqrt(sum v[row][i]^2) ----------------
__global__ void norm_kernel(const float* __restrict__ v, float* __restrict__ nrm, int cin) {
    int row = blockIdx.x;
    const float* vr = v + (size_t)row * cin;
    float s = 0.f;
    for (int i = threadIdx.x; i < cin; i += 256) {
        float x = vr[i];
        s = __fadd_rn(s, __fmul_rn(x, x));
    }
    __shared__ float red[256];
    red[threadIdx.x] = s;
    __syncthreads();
    for (int off = 128; off > 0; off >>= 1) {
        if (threadIdx.x < off) red[threadIdx.x] += red[threadIdx.x + off];
        __syncthreads();
    }
    if (threadIdx.x == 0) nrm[row] = sqrtf(red[0]);
}

// ------------- transpose + weight-norm scale: wt[i][o] = (v[o][i]*g[o])/nrm[o] -------------
template<int WS>
__global__ void trans_kernel(const float* __restrict__ v, const float* __restrict__ g,
                             const float* __restrict__ nrm, float* __restrict__ wt,
                             int RO, int CI) {
    __shared__ float tile[32][33];
    int i0 = blockIdx.x * 32, o0 = blockIdx.y * 32;
    int tx = threadIdx.x, ty = threadIdx.y;
    for (int k = 0; k < 32; k += 8) {
        int o = o0 + ty + k, i = i0 + tx;
        float val = 0.f;
        if (o < RO) val = __fmul_rn(v[(size_t)o * CI + i], g[o]) / nrm[o];
        tile[ty + k][tx] = val;
    }
    __syncthreads();
    for (int k = 0; k < 32; k += 8) {
        int i = i0 + ty + k, oo = o0 + tx;
        if (oo < WS) wt[(size_t)i * WS + oo] = tile[tx][ty + k];
    }
}

// ------------- sparse spike GEMM, TG=4, per-t u16 lists, float2 outputs -------------
// Grid (b, tg): 16 x 75 blocks, 256 threads (4 waves). Wave wv builds segments
// 2wv and 2wv+1: for each of the 4 timesteps a ballot-compacted u16 list of
// active columns (i-ascending, deterministic). Walk: thread owns outputs
// o=2tid,2tid+1; per event exactly one float2 load of wt + 2 adds into
// statically-indexed register accumulators. Sum order per (t,o): segment
// ascending, i ascending — identical to prior passing kernels (exact).
template<int NI, int WS, bool FP32IN>
__global__ __launch_bounds__(256) void z4_kernel(const void* __restrict__ xin,
                                                 const float* __restrict__ wt,
                                                 float* __restrict__ zout) {
    constexpr int SEG  = NI / 8;                       // i-range per segment
    constexpr int CAPT = (NI >= 4096) ? 96 : SEG;      // per-(seg,t) list cap; 96 = 17 sigma @ p=0.02
    constexpr int NCH  = SEG / 64;
    __shared__ uint16_t act[8][4][CAPT];
    __shared__ int      cnt[8][4];

    int b = blockIdx.x, tg = blockIdx.y, t0 = tg * TG4;
    int tid = threadIdx.x, lane = tid & 63, wv = tid >> 6;

    // ---- build per-t lists (wave wv owns segments 2wv, 2wv+1) ----
    for (int ss = 0; ss < 2; ++ss) {
        int s = wv * 2 + ss;
        int cl[4] = {0, 0, 0, 0};
        for (int c = 0; c < NCH; ++c) {
            int i = s * SEG + c * 64 + lane;
            uint32_t m = 0;
            if (FP32IN) {
                const float* sp = (const float*)xin + ((size_t)(b * NI + i)) * TT + t0;
                float4 v4 = *(const float4*)sp;   // row stride 1200B, t0*4 multiple of 16 -> aligned
                m |= (v4.x != 0.f) ? 1u : 0u;
                m |= (v4.y != 0.f) ? 2u : 0u;
                m |= (v4.z != 0.f) ? 4u : 0u;
                m |= (v4.w != 0.f) ? 8u : 0u;
            } else {
                const uint8_t* sp = (const uint8_t*)xin + ((size_t)b * TT + t0) * NI + i;
                #pragma unroll
                for (int k = 0; k < 4; ++k)
                    m |= (sp[(size_t)k * NI] != 0) ? (1u << k) : 0u;
            }
            #pragma unroll
            for (int t = 0; t < 4; ++t) {          // t is compile-time after unroll
                uint32_t bit = (m >> t) & 1u;
                uint64_t bal = __ballot(bit != 0);
                int pos = __popcll(bal & ((1ull << lane) - 1ull));
                if (bit) {
                    int p = cl[t] + pos;
                    if (p < CAPT) act[s][t][p] = (uint16_t)i;
                }
                cl[t] += (int)__popcll(bal);
                if (NI >= 4096 && cl[t] > CAPT) cl[t] = CAPT;
            }
        }
        if (lane == 0) {
            #pragma unroll
            for (int t = 0; t < 4; ++t) cnt[s][t] = cl[t];
        }
    }
    __syncthreads();

    // ---- walk: 1 float2 load + 2 adds per event ----
    float a[4][2] = {{0.f,0.f},{0.f,0.f},{0.f,0.f},{0.f,0.f}};
    if (2 * tid < WS) {
        const float* wp = wt + 2 * tid;
        for (int s = 0; s < 8; ++s) {
            #pragma unroll
            for (int t = 0; t < 4; ++t) {
                int nb = cnt[s][t];
                const uint16_t* lp = &act[s][t][0];
                int j = 0;
                for (; j + 8 <= nb; j += 8) {
                    uint4 g4 = *(const uint4*)(lp + j);   // broadcast b128, 16B-aligned
                    uint32_t e0 = g4.x & 0xFFFFu, e1 = g4.x >> 16;
                    uint32_t e2 = g4.y & 0xFFFFu, e3 = g4.y >> 16;
                    uint32_t e4 = g4.z & 0xFFFFu, e5 = g4.z >> 16;
                    uint32_t e6 = g4.w & 0xFFFFu, e7 = g4.w >> 16;
                    float2 w0 = *(const float2*)(wp + (size_t)e0 * WS);
                    float2 w1 = *(const float2*)(wp + (size_t)e1 * WS);
                    float2 w2 = *(const float2*)(wp + (size_t)e2 * WS);
                    float2 w3 = *(const float2*)(wp + (size_t)e3 * WS);
                    float2 w4 = *(const float2*)(wp + (size_t)e4 * WS);
                    float2 w5 = *(const float2*)(wp + (size_t)e5 * WS);
                    float2 w6 = *(const float2*)(wp + (size_t)e6 * WS);
                    float2 w7 = *(const float2*)(wp + (size_t)e7 * WS);
                    a[t][0] += w0.x; a[t][1] += w0.y;
                    a[t][0] += w1.x; a[t][1] += w1.y;
                    a[t][0] += w2.x; a[t][1] += w2.y;
                    a[t][0] += w3.x; a[t][1] += w3.y;
                    a[t][0] += w4.x; a[t][1] += w4.y;
                    a[t][0] += w5.x; a[t][1] += w5.y;
                    a[t][0] += w6.x; a[t][1] += w6.y;
                    a[t][0] += w7.x; a[t][1] += w7.y;
                }
                for (; j < nb; ++j) {
                    uint32_t e = lp[j];
                    float2 w = *(const float2*)(wp + (size_t)e * WS);
                    a[t][0] += w.x; a[t][1] += w.y;
                }
            }
        }
        #pragma unroll
        for (int t = 0; t < 4; ++t)
            *(float2*)(zout + ((size_t)b * TT + t0 + t) * WS + 2 * tid) =
                make_float2(a[t][0], a[t][1]);
    }
}

// ---------------- CUBA-LIF scan, hidden layers (u8 spikes out), pipelined ----------------
__global__ __launch_bounds__(64) void lif_hidden_kernel(const float* __restrict__ z,
                                                        uint8_t* __restrict__ x,
                                                        const float* __restrict__ cdarr,
                                                        const float* __restrict__ vdarr,
                                                        int li) {
    int gid = blockIdx.x * 64 + threadIdx.x;
    if (gid >= NB * CHID) return;
    int b = gid >> 9, o = gid & 511;
    float omc = 1.0f - cdarr[li];
    float omv = 1.0f - vdarr[li];
    float cur = 0.f, volt = 0.f;
    const float* zp = z + (size_t)b * TT * CHID + o;
    uint8_t* xp = x + (size_t)b * TT * CHID + o;

    float A[10], Bv[10];
    auto loadg = [&](float (&buf)[10], int g) {
        #pragma unroll
        for (int k = 0; k < 10; ++k) buf[k] = zp[(size_t)(g * 10 + k) * CHID];
    };
    auto stepg = [&](float (&buf)[10], int g) {
        #pragma unroll
        for (int k = 0; k < 10; ++k) {
            cur  = __fadd_rn(__fmul_rn(omc, cur), buf[k]);
            volt = __fadd_rn(__fmul_rn(omv, volt), cur);
            bool s = (volt >= 1.25f);
            volt = s ? 0.f : volt;
            xp[(size_t)(g * 10 + k) * CHID] = s ? (uint8_t)1 : (uint8_t)0;
        }
    };
    loadg(A, 0);
    for (int g = 0; g < 30; g += 2) {
        if (g + 1 < 30) loadg(Bv, g + 1);
        stepg(A, g);
        if (g + 2 < 30) loadg(A, g + 2);
        if (g + 1 < 30) stepg(Bv, g + 1);
    }
}

// ---------------- CUBA-LIF final layer -> d_out [B][COUT][T] float, pipelined ----------------
__global__ __launch_bounds__(64) void lif_out_kernel(const float* __restrict__ z,
                                                     float* __restrict__ out,
                                                     const float* __restrict__ cdarr,
                                                     const float* __restrict__ vdarr,
                                                     int li) {
    int gid = blockIdx.x * 64 + threadIdx.x;
    if (gid >= NB * COUT) return;
    int b = gid / COUT, o = gid % COUT;
    float omc = 1.0f - cdarr[li];
    float omv = 1.0f - vdarr[li];
    float cur = 0.f, volt = 0.f;
    const float* zp = z + (size_t)b * TT * 128 + o;
    float* op = out + ((size_t)b * COUT + o) * TT;

    float A[10], Bv[10];
    auto loadg = [&](float (&buf)[10], int g) {
        #pragma unroll
        for (int k = 0; k < 10; ++k) buf[k] = zp[(size_t)(g * 10 + k) * 128];
    };
    auto stepg = [&](float (&buf)[10], int g) {
        #pragma unroll
        for (int k = 0; k < 10; ++k) {
            cur  = __fadd_rn(__fmul_rn(omc, cur), buf[k]);
            volt = __fadd_rn(__fmul_rn(omv, volt), cur);
            bool s = (volt >= 1.25f);
            volt = s ? 0.f : volt;
            op[g * 10 + k] = s ? 1.0f : 0.0f;
        }
    };
    loadg(A, 0);
    for (int g = 0; g < 30; g += 2) {
        if (g + 1 < 30) loadg(Bv, g + 1);
        stepg(A, g);
        if (g + 2 < 30) loadg(A, g + 2);
        if (g + 1 < 30) stepg(Bv, g + 1);
    }
}

extern "C" void kernel_launch(void* const* d_in, const int* in_sizes, int n_in,
                              void* d_out, int out_size, void* d_ws, size_t ws_size,
                              hipStream_t stream) {
    const float* spike = (const float*)d_in[0];
    const float* v1 = (const float*)d_in[1];
    const float* g1 = (const float*)d_in[2];
    const float* v2 = (const float*)d_in[3];
    const float* g2 = (const float*)d_in[4];
    const float* v3 = (const float*)d_in[5];
    const float* g3 = (const float*)d_in[6];
    const float* cd = (const float*)d_in[7];
    const float* vd = (const float*)d_in[8];

    // workspace layout (floats)
    float* ws   = (float*)d_ws;
    float* w1t  = ws;                            // [8192][512]
    float* w2t  = w1t + (size_t)CIN * CHID;      // [512][512]
    float* w3t  = w2t + (size_t)CHID * CHID;     // [512][128]
    float* nrm1 = w3t + (size_t)CHID * 128;      // 512
    float* nrm2 = nrm1 + 512;                    // 512
    float* nrm3 = nrm2 + 512;                    // 128
    float* zbuf = nrm3 + 128;                    // [16][300][512] (z1 then z2)
    float* z3   = zbuf + (size_t)NB * TT * CHID; // [16][300][128]
    uint8_t* x1 = (uint8_t*)(z3 + (size_t)NB * TT * 128);
    uint8_t* x2 = x1 + (size_t)NB * TT * CHID;
    size_t need = (size_t)(x2 + (size_t)NB * TT * CHID - (uint8_t*)d_ws);
    if (ws_size < need) return;  // fail loudly via wrong output rather than corrupt

    // weight prep
    norm_kernel<<<dim3(CHID), dim3(256), 0, stream>>>(v1, nrm1, CIN);
    norm_kernel<<<dim3(CHID), dim3(256), 0, stream>>>(v2, nrm2, CHID);
    norm_kernel<<<dim3(COUT), dim3(256), 0, stream>>>(v3, nrm3, CHID);
    trans_kernel<512><<<dim3(CIN / 32, CHID / 32), dim3(32, 8), 0, stream>>>(v1, g1, nrm1, w1t, CHID, CIN);
    trans_kernel<512><<<dim3(CHID / 32, CHID / 32), dim3(32, 8), 0, stream>>>(v2, g2, nrm2, w2t, CHID, CHID);
    trans_kernel<128><<<dim3(CHID / 32, 4), dim3(32, 8), 0, stream>>>(v3, g3, nrm3, w3t, COUT, CHID);

    dim3 zgrid(NB, NTG4);   // b fastest: tg-adjacent blocks share XCD (delta bid = 16 == 0 mod 8)
    // layer 1
    z4_kernel<CIN, 512, true><<<zgrid, 256, 0, stream>>>(spike, w1t, zbuf);
    lif_hidden_kernel<<<dim3(NB * CHID / 64), dim3(64), 0, stream>>>(zbuf, x1, cd, vd, 0);
    // layer 2
    z4_kernel<CHID, 512, false><<<zgrid, 256, 0, stream>>>(x1, w2t, zbuf);
    lif_hidden_kernel<<<dim3(NB * CHID / 64), dim3(64), 0, stream>>>(zbuf, x2, cd, vd, 1);
    // layer 3
    z4_kernel<CHID, 128, false><<<zgrid, 256, 0, stream>>>(x2, w3t, z3);
    lif_out_kernel<<<dim3((NB * COUT + 63) / 64), dim3(64), 0, stream>>>(z3, (float*)d_out, cd, vd, 2);
}

// Round 5
// 251.491 us; speedup vs baseline: 3.7031x; 1.0727x over previous
//
#include <hip/hip_runtime.h>
#include <stdint.h>
#include <math.h>

#define NB   16
#define CIN  8192
#define CHID 512
#define COUT 100
#define TT   300
#define TG4  4
#define NTG4 75   // 300/4
#define NW1  256  // mask words per (b,t): 8192/32; also event-list capacity

// ---------------- row norms: nrm[row] = sqrt(sum v[row][i]^2) ----------------
__global__ void norm_kernel(const float* __restrict__ v, float* __restrict__ nrm, int cin) {
    int row = blockIdx.x;
    const float* vr = v + (size_t)row * cin;
    float s = 0.f;
    for (int i = threadIdx.x; i < cin; i += 256) {
        float x = vr[i];
        s = __fadd_rn(s, __fmul_rn(x, x));
    }
    __shared__ float red[256];
    red[threadIdx.x] = s;
    __syncthreads();
    for (int off = 128; off > 0; off >>= 1) {
        if (threadIdx.x < off) red[threadIdx.x] += red[threadIdx.x + off];
        __syncthreads();
    }
    if (threadIdx.x == 0) nrm[row] = sqrtf(red[0]);
}

// ------------- transpose + weight-norm scale: wt[i][o] = (v[o][i]*g[o])/nrm[o] -------------
template<int WS>
__global__ void trans_kernel(const float* __restrict__ v, const float* __restrict__ g,
                             const float* __restrict__ nrm, float* __restrict__ wt,
                             int RO, int CI) {
    __shared__ float tile[32][33];
    int i0 = blockIdx.x * 32, o0 = blockIdx.y * 32;
    int tx = threadIdx.x, ty = threadIdx.y;
    for (int k = 0; k < 32; k += 8) {
        int o = o0 + ty + k, i = i0 + tx;
        float val = 0.f;
        if (o < RO) val = __fmul_rn(v[(size_t)o * CI + i], g[o]) / nrm[o];
        tile[ty + k][tx] = val;
    }
    __syncthreads();
    for (int k = 0; k < 32; k += 8) {
        int i = i0 + ty + k, oo = o0 + tx;
        if (oo < WS) wt[(size_t)i * WS + oo] = tile[tx][ty + k];
    }
}

// ------------- spike[b][i][t] fp32 -> bit-transposed maskT[b][t][i/32] -------------
// Block (b, itile of 64 i). LDS-staged transpose: coalesced float4 reads,
// then 128 threads build one u32 word (32 consecutive i) each per t.
__global__ __launch_bounds__(256) void mask_kernel(const float* __restrict__ spike,
                                                   uint32_t* __restrict__ maskT) {
    __shared__ uint32_t flag[64][16];  // [i_local][t_local/4], 4 u8 flags packed per word
    int b = blockIdx.x, itile = blockIdx.y;
    int tid = threadIdx.x;
    int row = tid >> 2, qc = tid & 3;
    const float* sp = spike + ((size_t)(b * CIN + itile * 64 + row)) * TT;
    for (int tc = 0; tc < 5; ++tc) {
        #pragma unroll
        for (int k = 0; k < 4; ++k) {
            int t0 = tc * 64 + k * 16 + qc * 4;   // 4 lanes x 16B = 64B contiguous per row
            uint32_t packed = 0;
            if (t0 + 3 < TT) {
                float4 v = *(const float4*)(sp + t0);   // 1200B row stride, 16B aligned
                packed = (v.x != 0.f ? 1u : 0u) | (v.y != 0.f ? 0x100u : 0u)
                       | (v.z != 0.f ? 0x10000u : 0u) | (v.w != 0.f ? 0x1000000u : 0u);
            }
            flag[row][k * 4 + qc] = packed;
        }
        __syncthreads();
        if (tid < 128) {
            int t_l = tid >> 1, half = tid & 1;
            int t = tc * 64 + t_l;
            if (t < TT) {
                uint32_t word = 0;
                #pragma unroll
                for (int k = 0; k < 32; ++k) {
                    uint32_t f = flag[half * 32 + k][t_l >> 2];
                    word |= (((f >> ((t_l & 3) * 8)) & 1u) << k);
                }
                maskT[((size_t)b * TT + t) * NW1 + itile * 2 + half] = word;
            }
        }
        __syncthreads();
    }
}

// ------------- maskT -> per-(b,t) ordered event list (u16 col ids) + count -------------
// One wave per (b,t). Lane parses words [4*lane .. 4*lane+3]; wave prefix-sum of
// popcounts gives each lane's write offset -> globally i-ascending list. Deterministic.
__global__ __launch_bounds__(256) void evlist1_kernel(const uint32_t* __restrict__ maskT,
                                                      uint16_t* __restrict__ ev,
                                                      uint32_t* __restrict__ cnt) {
    int b = blockIdx.x, tg = blockIdx.y;
    int tid = threadIdx.x, lane = tid & 63, wv = tid >> 6;
    int t = tg * TG4 + wv;
    const uint32_t* mrow = maskT + ((size_t)b * TT + t) * NW1;
    uint4 w4 = *(const uint4*)(mrow + lane * 4);
    int c = __popc(w4.x) + __popc(w4.y) + __popc(w4.z) + __popc(w4.w);
    int off = c;
    for (int d = 1; d < 64; d <<= 1) {
        int n = __shfl_up(off, d, 64);
        if (lane >= d) off += n;
    }
    int total = __shfl(off, 63, 64);
    off -= c;  // exclusive prefix
    uint16_t* erow = ev + ((size_t)b * TT + t) * NW1;
    uint32_t wsv[4] = {w4.x, w4.y, w4.z, w4.w};
    int base_i = lane * 128;
    #pragma unroll
    for (int wi = 0; wi < 4; ++wi) {
        uint32_t m = wsv[wi];
        while (m) {
            int bpos = __builtin_ctz(m);
            m &= m - 1;
            if (off < NW1) erow[off] = (uint16_t)(base_i + wi * 32 + bpos);
            ++off;
        }
    }
    if (lane == 63) cnt[(size_t)b * TT + t] = (uint32_t)(total < NW1 ? total : NW1);
}

// ------------- layer-1 gather: z[b][t][o] = sum_{i in evlist(b,t)} wt[i][o] -------------
// Grid (4 oslice, 16 b, 75 tg), 256 threads = 4 waves; wave = one t, lanes cover
// 128 outputs (float2). gridDim.x=4 pins each o-slice to fixed XCDs (bid%8) so the
// 4MB wt slice stays L2-resident per XCD. Event order i-ascending -> exact sums.
template<int WS, int OSW>
__global__ __launch_bounds__(256) void zg_kernel(const uint16_t* __restrict__ ev,
                                                 const uint32_t* __restrict__ cnt,
                                                 const float* __restrict__ wt,
                                                 float* __restrict__ zout) {
    int oslice = blockIdx.x, b = blockIdx.y, tg = blockIdx.z;
    int tid = threadIdx.x, lane = tid & 63, wv = tid >> 6;
    int t = tg * TG4 + wv;
    int obase = oslice * OSW + lane * 2;
    const uint16_t* erow = ev + ((size_t)b * TT + t) * NW1;
    int n = (int)cnt[(size_t)b * TT + t];
    const float* wp = wt + obase;
    float a0 = 0.f, a1 = 0.f;
    int j = 0;
    for (; j + 8 <= n; j += 8) {
        uint4 g = *(const uint4*)(erow + j);   // 16B-aligned (row base 512B, j%8==0)
        uint32_t e0 = g.x & 0xFFFFu, e1 = g.x >> 16;
        uint32_t e2 = g.y & 0xFFFFu, e3 = g.y >> 16;
        uint32_t e4 = g.z & 0xFFFFu, e5 = g.z >> 16;
        uint32_t e6 = g.w & 0xFFFFu, e7 = g.w >> 16;
        float2 w0 = *(const float2*)(wp + (size_t)e0 * WS);
        float2 w1 = *(const float2*)(wp + (size_t)e1 * WS);
        float2 w2 = *(const float2*)(wp + (size_t)e2 * WS);
        float2 w3 = *(const float2*)(wp + (size_t)e3 * WS);
        float2 w4 = *(const float2*)(wp + (size_t)e4 * WS);
        float2 w5 = *(const float2*)(wp + (size_t)e5 * WS);
        float2 w6 = *(const float2*)(wp + (size_t)e6 * WS);
        float2 w7 = *(const float2*)(wp + (size_t)e7 * WS);
        a0 += w0.x; a1 += w0.y;
        a0 += w1.x; a1 += w1.y;
        a0 += w2.x; a1 += w2.y;
        a0 += w3.x; a1 += w3.y;
        a0 += w4.x; a1 += w4.y;
        a0 += w5.x; a1 += w5.y;
        a0 += w6.x; a1 += w6.y;
        a0 += w7.x; a1 += w7.y;
    }
    for (; j < n; ++j) {
        uint32_t e = erow[j];
        float2 w = *(const float2*)(wp + (size_t)e * WS);
        a0 += w.x; a1 += w.y;
    }
    *(float2*)(zout + ((size_t)b * TT + t) * WS + obase) = make_float2(a0, a1);
}

// ------------- sparse spike GEMM for layers 2/3 (u8 input), per-t u16 lists -------------
template<int NI, int WS, bool FP32IN>
__global__ __launch_bounds__(256) void z4_kernel(const void* __restrict__ xin,
                                                 const float* __restrict__ wt,
                                                 float* __restrict__ zout) {
    constexpr int SEG  = NI / 8;
    constexpr int CAPT = (NI >= 4096) ? 96 : SEG;
    constexpr int NCH  = SEG / 64;
    __shared__ uint16_t act[8][4][CAPT];
    __shared__ int      cnt[8][4];

    int b = blockIdx.x, tg = blockIdx.y, t0 = tg * TG4;
    int tid = threadIdx.x, lane = tid & 63, wv = tid >> 6;

    for (int ss = 0; ss < 2; ++ss) {
        int s = wv * 2 + ss;
        int cl[4] = {0, 0, 0, 0};
        for (int c = 0; c < NCH; ++c) {
            int i = s * SEG + c * 64 + lane;
            uint32_t m = 0;
            if (FP32IN) {
                const float* sp = (const float*)xin + ((size_t)(b * NI + i)) * TT + t0;
                float4 v4 = *(const float4*)sp;
                m |= (v4.x != 0.f) ? 1u : 0u;
                m |= (v4.y != 0.f) ? 2u : 0u;
                m |= (v4.z != 0.f) ? 4u : 0u;
                m |= (v4.w != 0.f) ? 8u : 0u;
            } else {
                const uint8_t* sp = (const uint8_t*)xin + ((size_t)b * TT + t0) * NI + i;
                #pragma unroll
                for (int k = 0; k < 4; ++k)
                    m |= (sp[(size_t)k * NI] != 0) ? (1u << k) : 0u;
            }
            #pragma unroll
            for (int t = 0; t < 4; ++t) {
                uint32_t bit = (m >> t) & 1u;
                uint64_t bal = __ballot(bit != 0);
                int pos = __popcll(bal & ((1ull << lane) - 1ull));
                if (bit) {
                    int p = cl[t] + pos;
                    if (p < CAPT) act[s][t][p] = (uint16_t)i;
                }
                cl[t] += (int)__popcll(bal);
                if (NI >= 4096 && cl[t] > CAPT) cl[t] = CAPT;
            }
        }
        if (lane == 0) {
            #pragma unroll
            for (int t = 0; t < 4; ++t) cnt[s][t] = cl[t];
        }
    }
    __syncthreads();

    float a[4][2] = {{0.f,0.f},{0.f,0.f},{0.f,0.f},{0.f,0.f}};
    if (2 * tid < WS) {
        const float* wp = wt + 2 * tid;
        for (int s = 0; s < 8; ++s) {
            #pragma unroll
            for (int t = 0; t < 4; ++t) {
                int nb = cnt[s][t];
                const uint16_t* lp = &act[s][t][0];
                int j = 0;
                for (; j + 8 <= nb; j += 8) {
                    uint4 g4 = *(const uint4*)(lp + j);
                    uint32_t e0 = g4.x & 0xFFFFu, e1 = g4.x >> 16;
                    uint32_t e2 = g4.y & 0xFFFFu, e3 = g4.y >> 16;
                    uint32_t e4 = g4.z & 0xFFFFu, e5 = g4.z >> 16;
                    uint32_t e6 = g4.w & 0xFFFFu, e7 = g4.w >> 16;
                    float2 w0 = *(const float2*)(wp + (size_t)e0 * WS);
                    float2 w1 = *(const float2*)(wp + (size_t)e1 * WS);
                    float2 w2 = *(const float2*)(wp + (size_t)e2 * WS);
                    float2 w3 = *(const float2*)(wp + (size_t)e3 * WS);
                    float2 w4 = *(const float2*)(wp + (size_t)e4 * WS);
                    float2 w5 = *(const float2*)(wp + (size_t)e5 * WS);
                    float2 w6 = *(const float2*)(wp + (size_t)e6 * WS);
                    float2 w7 = *(const float2*)(wp + (size_t)e7 * WS);
                    a[t][0] += w0.x; a[t][1] += w0.y;
                    a[t][0] += w1.x; a[t][1] += w1.y;
                    a[t][0] += w2.x; a[t][1] += w2.y;
                    a[t][0] += w3.x; a[t][1] += w3.y;
                    a[t][0] += w4.x; a[t][1] += w4.y;
                    a[t][0] += w5.x; a[t][1] += w5.y;
                    a[t][0] += w6.x; a[t][1] += w6.y;
                    a[t][0] += w7.x; a[t][1] += w7.y;
                }
                for (; j < nb; ++j) {
                    uint32_t e = lp[j];
                    float2 w = *(const float2*)(wp + (size_t)e * WS);
                    a[t][0] += w.x; a[t][1] += w.y;
                }
            }
        }
        #pragma unroll
        for (int t = 0; t < 4; ++t)
            *(float2*)(zout + ((size_t)b * TT + t0 + t) * WS + 2 * tid) =
                make_float2(a[t][0], a[t][1]);
    }
}

// ---------------- CUBA-LIF scan, hidden layers (u8 spikes out), pipelined ----------------
__global__ __launch_bounds__(64) void lif_hidden_kernel(const float* __restrict__ z,
                                                        uint8_t* __restrict__ x,
                                                        const float* __restrict__ cdarr,
                                                        const float* __restrict__ vdarr,
                                                        int li) {
    int gid = blockIdx.x * 64 + threadIdx.x;
    if (gid >= NB * CHID) return;
    int b = gid >> 9, o = gid & 511;
    float omc = 1.0f - cdarr[li];
    float omv = 1.0f - vdarr[li];
    float cur = 0.f, volt = 0.f;
    const float* zp = z + (size_t)b * TT * CHID + o;
    uint8_t* xp = x + (size_t)b * TT * CHID + o;

    float A[10], Bv[10];
    auto loadg = [&](float (&buf)[10], int g) {
        #pragma unroll
        for (int k = 0; k < 10; ++k) buf[k] = zp[(size_t)(g * 10 + k) * CHID];
    };
    auto stepg = [&](float (&buf)[10], int g) {
        #pragma unroll
        for (int k = 0; k < 10; ++k) {
            cur  = __fadd_rn(__fmul_rn(omc, cur), buf[k]);
            volt = __fadd_rn(__fmul_rn(omv, volt), cur);
            bool s = (volt >= 1.25f);
            volt = s ? 0.f : volt;
            xp[(size_t)(g * 10 + k) * CHID] = s ? (uint8_t)1 : (uint8_t)0;
        }
    };
    loadg(A, 0);
    for (int g = 0; g < 30; g += 2) {
        if (g + 1 < 30) loadg(Bv, g + 1);
        stepg(A, g);
        if (g + 2 < 30) loadg(A, g + 2);
        if (g + 1 < 30) stepg(Bv, g + 1);
    }
}

// ---------------- CUBA-LIF final layer -> d_out [B][COUT][T] float, pipelined ----------------
__global__ __launch_bounds__(64) void lif_out_kernel(const float* __restrict__ z,
                                                     float* __restrict__ out,
                                                     const float* __restrict__ cdarr,
                                                     const float* __restrict__ vdarr,
                                                     int li) {
    int gid = blockIdx.x * 64 + threadIdx.x;
    if (gid >= NB * COUT) return;
    int b = gid / COUT, o = gid % COUT;
    float omc = 1.0f - cdarr[li];
    float omv = 1.0f - vdarr[li];
    float cur = 0.f, volt = 0.f;
    const float* zp = z + (size_t)b * TT * 128 + o;
    float* op = out + ((size_t)b * COUT + o) * TT;

    float A[10], Bv[10];
    auto loadg = [&](float (&buf)[10], int g) {
        #pragma unroll
        for (int k = 0; k < 10; ++k) buf[k] = zp[(size_t)(g * 10 + k) * 128];
    };
    auto stepg = [&](float (&buf)[10], int g) {
        #pragma unroll
        for (int k = 0; k < 10; ++k) {
            cur  = __fadd_rn(__fmul_rn(omc, cur), buf[k]);
            volt = __fadd_rn(__fmul_rn(omv, volt), cur);
            bool s = (volt >= 1.25f);
            volt = s ? 0.f : volt;
            op[g * 10 + k] = s ? 1.0f : 0.0f;
        }
    };
    loadg(A, 0);
    for (int g = 0; g < 30; g += 2) {
        if (g + 1 < 30) loadg(Bv, g + 1);
        stepg(A, g);
        if (g + 2 < 30) loadg(A, g + 2);
        if (g + 1 < 30) stepg(Bv, g + 1);
    }
}

extern "C" void kernel_launch(void* const* d_in, const int* in_sizes, int n_in,
                              void* d_out, int out_size, void* d_ws, size_t ws_size,
                              hipStream_t stream) {
    const float* spike = (const float*)d_in[0];
    const float* v1 = (const float*)d_in[1];
    const float* g1 = (const float*)d_in[2];
    const float* v2 = (const float*)d_in[3];
    const float* g2 = (const float*)d_in[4];
    const float* v3 = (const float*)d_in[5];
    const float* g3 = (const float*)d_in[6];
    const float* cd = (const float*)d_in[7];
    const float* vd = (const float*)d_in[8];

    // workspace layout
    float* ws   = (float*)d_ws;
    float* w1t  = ws;                            // [8192][512]
    float* w2t  = w1t + (size_t)CIN * CHID;      // [512][512]
    float* w3t  = w2t + (size_t)CHID * CHID;     // [512][128]
    float* nrm1 = w3t + (size_t)CHID * 128;      // 512
    float* nrm2 = nrm1 + 512;                    // 512
    float* nrm3 = nrm2 + 512;                    // 128
    float* zbuf = nrm3 + 128;                    // [16][300][512]
    float* z3   = zbuf + (size_t)NB * TT * CHID; // [16][300][128]
    uint8_t*  x1    = (uint8_t*)(z3 + (size_t)NB * TT * 128);
    uint8_t*  x2    = x1 + (size_t)NB * TT * CHID;
    uint32_t* maskT = (uint32_t*)(x2 + (size_t)NB * TT * CHID);   // [16][300][256]
    uint16_t* ev1   = (uint16_t*)(maskT + (size_t)NB * TT * NW1); // [16][300][256]
    uint32_t* cnt1  = (uint32_t*)(ev1 + (size_t)NB * TT * NW1);   // [16][300]
    size_t need = (size_t)((uint8_t*)(cnt1 + (size_t)NB * TT) - (uint8_t*)d_ws);
    if (ws_size < need) return;  // fail loudly via wrong output rather than corrupt

    // weight prep
    norm_kernel<<<dim3(CHID), dim3(256), 0, stream>>>(v1, nrm1, CIN);
    norm_kernel<<<dim3(CHID), dim3(256), 0, stream>>>(v2, nrm2, CHID);
    norm_kernel<<<dim3(COUT), dim3(256), 0, stream>>>(v3, nrm3, CHID);
    trans_kernel<512><<<dim3(CIN / 32, CHID / 32), dim3(32, 8), 0, stream>>>(v1, g1, nrm1, w1t, CHID, CIN);
    trans_kernel<512><<<dim3(CHID / 32, CHID / 32), dim3(32, 8), 0, stream>>>(v2, g2, nrm2, w2t, CHID, CHID);
    trans_kernel<128><<<dim3(CHID / 32, 4), dim3(32, 8), 0, stream>>>(v3, g3, nrm3, w3t, COUT, CHID);

    // layer 1: bit-transpose -> event lists -> XCD-partitioned gather
    mask_kernel<<<dim3(NB, CIN / 64), dim3(256), 0, stream>>>(spike, maskT);
    evlist1_kernel<<<dim3(NB, NTG4), dim3(256), 0, stream>>>(maskT, ev1, cnt1);
    zg_kernel<512, 128><<<dim3(4, NB, NTG4), dim3(256), 0, stream>>>(ev1, cnt1, w1t, zbuf);
    lif_hidden_kernel<<<dim3(NB * CHID / 64), dim3(64), 0, stream>>>(zbuf, x1, cd, vd, 0);
    // layer 2
    z4_kernel<CHID, 512, false><<<dim3(NB, NTG4), 256, 0, stream>>>(x1, w2t, zbuf);
    lif_hidden_kernel<<<dim3(NB * CHID / 64), dim3(64), 0, stream>>>(zbuf, x2, cd, vd, 1);
    // layer 3
    z4_kernel<CHID, 128, false><<<dim3(NB, NTG4), 256, 0, stream>>>(x2, w3t, z3);
    lif_out_kernel<<<dim3((NB * COUT + 63) / 64), dim3(64), 0, stream>>>(z3, (float*)d_out, cd, vd, 2);
}